// Round 1
// baseline (395.490 us; speedup 1.0000x reference)
//
#include <hip/hip_runtime.h>

typedef unsigned short u16;
typedef unsigned int u32;
typedef __attribute__((ext_vector_type(8))) short bf16x8;
typedef __attribute__((ext_vector_type(4))) float f32x4;

#define NPATCH 81920
#define NBATCH 4
#define DLAT 32
#define HID 128
#define NROWS (NBATCH * NPATCH)   // 327680
#define CHUNK 128
#define NCHUNK (NROWS / CHUNK)    // 2560
#define CPB (NPATCH / CHUNK)      // 640 chunks per batch
#define SA 136                    // LDS row stride in bf16 elems (272B: 17*16B -> uniform bank slots)
#define STEPGRID 512              // 2 blocks/CU * 256 CUs

__device__ __forceinline__ u32 f2u(float f) { union { float f; u32 u; } c; c.f = f; return c.u; }
__device__ __forceinline__ float u2f(u32 u) { union { u32 u; float f; } c; c.u = u; return c.f; }
// round-to-nearest-even fp32 -> bf16 bits
__device__ __forceinline__ u16 bf_rne(float x) {
  u32 u = f2u(x);
  return (u16)((u + 0x7FFFu + ((u >> 16) & 1u)) >> 16);
}

// ---------------- prep: split W1 (k-permuted, fragment-ordered) and W2^T into bf16 hi/lo ----------------
// wf layout: [part(2)][kg(16)][n(128)][j(8)] bf16, k' = kg*8+j, k' = s*32+d maps to W1 row d*4+s
// w2t layout: [part(2)][o(16)][k(128)] bf16
__global__ void prep_kernel(const float* __restrict__ W1, const float* __restrict__ W2,
                            u16* __restrict__ wf, u16* __restrict__ w2t) {
  int t = blockIdx.x * 256 + threadIdx.x;
  if (t < 128 * 128) {
    int kp = t >> 7, n = t & 127;
    int s = kp >> 5, d = kp & 31;
    float v = W1[(d * 4 + s) * HID + n];
    u16 h = bf_rne(v);
    float rem = v - u2f((u32)h << 16);
    u16 l = bf_rne(rem);
    int kg = kp >> 3, j = kp & 7;
    int o = (kg * 128 + n) * 8 + j;
    wf[o] = h;
    wf[16384 + o] = l;
  } else if (t < 128 * 128 + 128 * 16) {
    int uu = t - 128 * 128;       // uu = k*16 + o
    int k = uu >> 4, o = uu & 15;
    float v = W2[k * 16 + o];
    u16 h = bf_rne(v);
    float rem = v - u2f((u32)h << 16);
    u16 l = bf_rne(rem);
    w2t[o * 128 + k] = h;
    w2t[2048 + o * 128 + k] = l;
  }
}

// ---------------- one solver step: zout = step(zin) ----------------
__global__ __launch_bounds__(256, 2) void step_kernel(
    const float* __restrict__ zin, float* __restrict__ zout,
    const int* __restrict__ nl, const float* __restrict__ b1,
    const float* __restrict__ b2, const u16* __restrict__ wf,
    const u16* __restrict__ w2t) {
  // A tile (re-used as h tile) + W2 tiles, all hi/lo bf16
  __shared__ __align__(16) u16 AH[CHUNK * SA];
  __shared__ __align__(16) u16 AL[CHUNK * SA];
  __shared__ __align__(16) u16 W2H[16 * SA];
  __shared__ __align__(16) u16 W2L[16 * SA];

  const int tid = threadIdx.x;
  const int lane = tid & 63;
  const int w = tid >> 6;      // wave 0..3
  const int li = lane & 15;
  const int lg = lane >> 4;    // 0..3

  // stage W2^T hi/lo into LDS (padded stride)
  #pragma unroll
  for (int c = 0; c < 2; ++c) {
    int idx = tid * 2 + c;               // 0..511
    int part = idx >> 8, rest = idx & 255;
    int o = rest >> 4, kc = rest & 15;
    bf16x8 v = *(const bf16x8*)&w2t[part * 2048 + o * 128 + kc * 8];
    u16* dst = part ? W2L : W2H;
    *(bf16x8*)&dst[o * SA + kc * 8] = v;
  }

  // W1 fragments resident in registers: wave w owns HIDDEN cols [32w, 32w+32)
  bf16x8 WH[2][4], WL[2][4];
  #pragma unroll
  for (int nt = 0; nt < 2; ++nt)
    #pragma unroll
    for (int kt = 0; kt < 4; ++kt) {
      int kg = kt * 4 + lg;
      int n = w * 32 + nt * 16 + li;
      WH[nt][kt] = *(const bf16x8*)&wf[(kg * 128 + n) * 8];
      WL[nt][kt] = *(const bf16x8*)&wf[16384 + (kg * 128 + n) * 8];
    }

  float b1v[2][4];
  #pragma unroll
  for (int nt = 0; nt < 2; ++nt)
    #pragma unroll
    for (int r = 0; r < 4; ++r)
      b1v[nt][r] = b1[w * 32 + nt * 16 + lg * 4 + r];
  float b2v = b2[li];

  for (int chunk = blockIdx.x; chunk < NCHUNK; chunk += gridDim.x) {
    int b = chunk / CPB;
    int row0 = chunk * CHUNK;             // global row base
    int pbase = row0 - b * NPATCH;        // patch index base within batch
    const float* zb = zin + (size_t)b * NPATCH * DLAT;

    __syncthreads();  // previous chunk's LDS reads done (also covers W2 staging on iter 0)

    // ---- stage: gather self + 3 neighbours, split to bf16 hi/lo in LDS ----
    // wave = source section (0=self, 1..3=neighbour), lane = row
    #pragma unroll
    for (int it = 0; it < 2; ++it) {
      int rl = it * 64 + lane;            // local row 0..127
      int p = pbase + rl;
      int ps = (w == 0) ? p : nl[p * 3 + (w - 1)];
      const float* src = zb + (size_t)ps * DLAT;
      float xs[32];
      #pragma unroll
      for (int q = 0; q < 8; ++q) {
        float4 vv = *(const float4*)&src[q * 4];
        xs[q * 4 + 0] = vv.x; xs[q * 4 + 1] = vv.y;
        xs[q * 4 + 2] = vv.z; xs[q * 4 + 3] = vv.w;
      }
      if (w == 0) {  // pass-through dims 16..31 of z
        float* dsto = zout + (size_t)(row0 + rl) * DLAT;
        *(float4*)&dsto[16] = make_float4(xs[16], xs[17], xs[18], xs[19]);
        *(float4*)&dsto[20] = make_float4(xs[20], xs[21], xs[22], xs[23]);
        *(float4*)&dsto[24] = make_float4(xs[24], xs[25], xs[26], xs[27]);
        *(float4*)&dsto[28] = make_float4(xs[28], xs[29], xs[30], xs[31]);
      }
      int base = rl * SA + w * 32;
      #pragma unroll
      for (int q = 0; q < 4; ++q) {
        bf16x8 hv, lv;
        #pragma unroll
        for (int e = 0; e < 8; ++e) {
          float x = xs[q * 8 + e];
          u16 h = bf_rne(x);
          float rem = x - u2f((u32)h << 16);
          hv[e] = (short)h;
          lv[e] = (short)bf_rne(rem);
        }
        *(bf16x8*)&AH[base + q * 8] = hv;
        *(bf16x8*)&AL[base + q * 8] = lv;
      }
    }
    __syncthreads();

    // ---- GEMM1 (transposed): D[n][m] = W1T @ flatT, bf16x3 split ----
    f32x4 acc[2][8];
    #pragma unroll
    for (int nt = 0; nt < 2; ++nt)
      #pragma unroll
      for (int mt = 0; mt < 8; ++mt)
        acc[nt][mt] = (f32x4){0.f, 0.f, 0.f, 0.f};

    #pragma unroll
    for (int kt = 0; kt < 4; ++kt) {
      #pragma unroll
      for (int mt = 0; mt < 8; ++mt) {
        int off = (mt * 16 + li) * SA + kt * 32 + lg * 8;
        bf16x8 ah = *(const bf16x8*)&AH[off];
        bf16x8 al = *(const bf16x8*)&AL[off];
        #pragma unroll
        for (int nt = 0; nt < 2; ++nt) {
          acc[nt][mt] = __builtin_amdgcn_mfma_f32_16x16x32_bf16(WH[nt][kt], ah, acc[nt][mt], 0, 0, 0);
          acc[nt][mt] = __builtin_amdgcn_mfma_f32_16x16x32_bf16(WH[nt][kt], al, acc[nt][mt], 0, 0, 0);
          acc[nt][mt] = __builtin_amdgcn_mfma_f32_16x16x32_bf16(WL[nt][kt], ah, acc[nt][mt], 0, 0, 0);
        }
      }
    }
    __syncthreads();  // all A reads done before h overwrites the same LDS

    // ---- bias + tanh + split, write h (row-major [m][n]) into AH/AL ----
    #pragma unroll
    for (int nt = 0; nt < 2; ++nt) {
      #pragma unroll
      for (int mt = 0; mt < 8; ++mt) {
        u32 hw0, hw1, lw0, lw1;
        u16 hh[4], ll[4];
        #pragma unroll
        for (int r = 0; r < 4; ++r) {
          float hval = acc[nt][mt][r] + b1v[nt][r];
          float e = __expf(2.0f * hval);
          float t = 1.0f - 2.0f / (e + 1.0f);
          u16 hb = bf_rne(t);
          float rem = t - u2f((u32)hb << 16);
          hh[r] = hb;
          ll[r] = bf_rne(rem);
        }
        hw0 = (u32)hh[0] | ((u32)hh[1] << 16);
        hw1 = (u32)hh[2] | ((u32)hh[3] << 16);
        lw0 = (u32)ll[0] | ((u32)ll[1] << 16);
        lw1 = (u32)ll[2] | ((u32)ll[3] << 16);
        int m = mt * 16 + li;
        int n = w * 32 + nt * 16 + lg * 4;
        uint2 hv2; hv2.x = hw0; hv2.y = hw1;
        uint2 lv2; lv2.x = lw0; lv2.y = lw1;
        *(uint2*)&AH[m * SA + n] = hv2;
        *(uint2*)&AL[m * SA + n] = lv2;
      }
    }
    __syncthreads();  // h visible to all waves

    // ---- GEMM2: F[m][o] = h @ W2, bf16x3 split; wave w owns rows [32w, 32w+32) ----
    f32x4 acc2[2];
    acc2[0] = (f32x4){0.f, 0.f, 0.f, 0.f};
    acc2[1] = (f32x4){0.f, 0.f, 0.f, 0.f};
    #pragma unroll
    for (int kt = 0; kt < 4; ++kt) {
      int woff = li * SA + kt * 32 + lg * 8;
      bf16x8 wh = *(const bf16x8*)&W2H[woff];
      bf16x8 wl = *(const bf16x8*)&W2L[woff];
      #pragma unroll
      for (int mt = 0; mt < 2; ++mt) {
        int off = (w * 32 + mt * 16 + li) * SA + kt * 32 + lg * 8;
        bf16x8 hh = *(const bf16x8*)&AH[off];
        bf16x8 hl = *(const bf16x8*)&AL[off];
        acc2[mt] = __builtin_amdgcn_mfma_f32_16x16x32_bf16(hh, wh, acc2[mt], 0, 0, 0);
        acc2[mt] = __builtin_amdgcn_mfma_f32_16x16x32_bf16(hl, wh, acc2[mt], 0, 0, 0);
        acc2[mt] = __builtin_amdgcn_mfma_f32_16x16x32_bf16(hh, wl, acc2[mt], 0, 0, 0);
      }
    }

    // ---- epilogue: z_out[:, :16] = z_in[:, :16] + F ----
    #pragma unroll
    for (int mt = 0; mt < 2; ++mt) {
      #pragma unroll
      for (int r = 0; r < 4; ++r) {
        int rowg = row0 + w * 32 + mt * 16 + lg * 4 + r;
        float F = acc2[mt][r] + b2v;
        size_t oi = (size_t)rowg * DLAT + li;
        zout[oi] = zin[oi] + F;
      }
    }
  }
}

extern "C" void kernel_launch(void* const* d_in, const int* in_sizes, int n_in,
                              void* d_out, int out_size, void* d_ws, size_t ws_size,
                              hipStream_t stream) {
  const float* z_old = (const float*)d_in[0];
  const int* nl = (const int*)d_in[1];
  const float* W1 = (const float*)d_in[2];
  const float* b1 = (const float*)d_in[3];
  const float* W2 = (const float*)d_in[4];
  const float* b2 = (const float*)d_in[5];
  float* out = (float*)d_out;

  u16* wf = (u16*)d_ws;               // 65536 B
  u16* w2t = wf + 32768;              // 8192 B
  const size_t zoff = 73728;
  const size_t zbytes = (size_t)NROWS * DLAT * sizeof(float);

  prep_kernel<<<72, 256, 0, stream>>>(W1, W2, wf, w2t);

  if (ws_size >= zoff + zbytes) {
    float* zbuf = (float*)((char*)d_ws + zoff);
    step_kernel<<<STEPGRID, 256, 0, stream>>>(z_old, zbuf, nl, b1, b2, wf, w2t);
    step_kernel<<<STEPGRID, 256, 0, stream>>>(zbuf, out, nl, b1, b2, wf, w2t);
    step_kernel<<<STEPGRID, 256, 0, stream>>>(out, zbuf, nl, b1, b2, wf, w2t);
    step_kernel<<<STEPGRID, 256, 0, stream>>>(zbuf, out, nl, b1, b2, wf, w2t);
  } else {
    // fallback: ping-pong through d_in[0] (harness restores it before every launch)
    float* zmut = (float*)d_in[0];
    step_kernel<<<STEPGRID, 256, 0, stream>>>(z_old, out, nl, b1, b2, wf, w2t);
    step_kernel<<<STEPGRID, 256, 0, stream>>>(out, zmut, nl, b1, b2, wf, w2t);
    step_kernel<<<STEPGRID, 256, 0, stream>>>(zmut, out, nl, b1, b2, wf, w2t);
    step_kernel<<<STEPGRID, 256, 0, stream>>>(out, zmut, nl, b1, b2, wf, w2t);
    hipMemcpyAsync(out, zmut, zbytes, hipMemcpyDeviceToDevice, stream);
  }
}